// Round 5
// baseline (95.415 us; speedup 1.0000x reference)
//
#include <hip/hip_runtime.h>

// QuantizationLayer: 3-bit successive-approximation soft ADC.
// Outputs flat: q [la], Q [la*3] (innermost dim = bit), Wn [6].
// R1: 149us @ 3.37 TB/s -- stride-48B Q stores uncoalesced.
// R2: 90.5us @ 5.56 TB/s -- LDS-staged coalesced Q stores.
// R3/R4: nontemporal + no-barrier: NEUTRAL (90.9us) -> not L2-alloc-limited.
// R5: 8 elems/thread (2x fx4): 2x MLP (2 loads + 8 stores in flight),
//     2x burst length per stream. Discriminates scheduler-limited vs
//     mixed-stream HBM cap (~5.5 TB/s). LDS 24KB, wave-local, no barrier.

typedef float fx4 __attribute__((ext_vector_type(4)));

__device__ __forceinline__ float fast_tanh(float z) {
    // tanh(z) = 1 - 2/(exp(2z)+1); saturates correctly at +/-inf.
    float e = __expf(2.0f * z);
    return 1.0f - 2.0f / (e + 1.0f);
}

__global__ void __launch_bounds__(256)
quant_kernel(const float* __restrict__ x,
             const float* __restrict__ W,
             const float* __restrict__ nz,
             float* __restrict__ out,
             int la /* = L*NUM_ADCS */) {
    // Two independent 12KB staging regions (one per fx4 group);
    // wave w owns [768w..768w+768) within each region.
    __shared__ float lds[6144];

    const float wn0 = W[0] + nz[0];
    const float wn1 = W[1] + nz[1];
    const float wn2 = W[2] + nz[2];
    const float wn3 = W[3] + nz[3];
    const float wn4 = W[4] + nz[4];
    const float wn5 = W[5] + nz[5];

    const float VR  = 0.225f;
    const float AMP = 10000.0f;
    const float DLT = 1e-30f;
    const float s2  = wn5 * VR;
    const float b1  = wn4 * VR;
    const float a1  = 0.5f * wn3 * VR;
    const float b0  = wn2 * VR;
    const float a01 = 0.5f * wn1 * VR;
    const float a02 = 0.5f * wn0 * VR;
    const float w0  = 0.5f * VR;
    const float w1  = VR;
    const float w2  = 2.0f * VR;

    const int  t    = threadIdx.x;
    const int  w    = t >> 6;          // wave id 0..3
    const int  l    = t & 63;          // lane id
    const long base = (long)blockIdx.x * 2048;   // elements per block
    float* __restrict__ Qout = out + (long)la;

    if (base + 2048 <= (long)la) {
        // ---- fast path: two fx4 groups per thread ----
        const fx4* xin = reinterpret_cast<const fx4*>(x + base);
        const fx4 xa = __builtin_nontemporal_load(xin + t);        // group 0
        const fx4 xb = __builtin_nontemporal_load(xin + t + 256);  // group 1

        float qa[4], qb[4], Qa[12], Qb[12];
        #pragma unroll
        for (int k = 0; k < 4; ++k) {
            {
                const float xe = xa[k];
                const float Q2 = fast_tanh(AMP * (xe - s2 + DLT));
                const float Q1 = fast_tanh(AMP * (xe - (b1 + (Q2 + 1.0f) * a1) + DLT));
                const float Q0 = fast_tanh(AMP * (xe - (b0 + (Q1 + 1.0f) * a01
                                                           + (Q2 + 1.0f) * a02) + DLT));
                qa[k] = (Q0 + 1.0f) * w0 + (Q1 + 1.0f) * w1 + (Q2 + 1.0f) * w2;
                Qa[k * 3 + 0] = Q0; Qa[k * 3 + 1] = Q1; Qa[k * 3 + 2] = Q2;
            }
            {
                const float xe = xb[k];
                const float Q2 = fast_tanh(AMP * (xe - s2 + DLT));
                const float Q1 = fast_tanh(AMP * (xe - (b1 + (Q2 + 1.0f) * a1) + DLT));
                const float Q0 = fast_tanh(AMP * (xe - (b0 + (Q1 + 1.0f) * a01
                                                           + (Q2 + 1.0f) * a02) + DLT));
                qb[k] = (Q0 + 1.0f) * w0 + (Q1 + 1.0f) * w1 + (Q2 + 1.0f) * w2;
                Qb[k * 3 + 0] = Q0; Qb[k * 3 + 1] = Q1; Qb[k * 3 + 2] = Q2;
            }
        }

        // q stores: two coalesced 16B/lane sweeps.
        fx4* qo = reinterpret_cast<fx4*>(out + base);
        __builtin_nontemporal_store((fx4){qa[0], qa[1], qa[2], qa[3]}, qo + t);
        __builtin_nontemporal_store((fx4){qb[0], qb[1], qb[2], qb[3]}, qo + t + 256);

        // Wave-local LDS staging, group 0 region [0,3072), group 1 [3072,6144).
        fx4* lpa = reinterpret_cast<fx4*>(&lds[t * 12]);
        lpa[0] = (fx4){Qa[0], Qa[1], Qa[2],  Qa[3]};
        lpa[1] = (fx4){Qa[4], Qa[5], Qa[6],  Qa[7]};
        lpa[2] = (fx4){Qa[8], Qa[9], Qa[10], Qa[11]};
        fx4* lpb = reinterpret_cast<fx4*>(&lds[3072 + t * 12]);
        lpb[0] = (fx4){Qb[0], Qb[1], Qb[2],  Qb[3]};
        lpb[1] = (fx4){Qb[4], Qb[5], Qb[6],  Qb[7]};
        lpb[2] = (fx4){Qb[8], Qb[9], Qb[10], Qb[11]};
        // No __syncthreads: waves read only their own regions.

        // Coalesced Q writes. Group 0 covers Q[base*3 .. base*3+3072),
        // group 1 the next 3072 floats. Wave w's chunk: 192 fx4 each.
        fx4* Qg0 = reinterpret_cast<fx4*>(Qout + base * 3) + w * 192;
        const fx4* lsa = reinterpret_cast<const fx4*>(&lds[w * 768]);
        __builtin_nontemporal_store(lsa[l],       Qg0 + l);
        __builtin_nontemporal_store(lsa[l + 64],  Qg0 + l + 64);
        __builtin_nontemporal_store(lsa[l + 128], Qg0 + l + 128);

        fx4* Qg1 = reinterpret_cast<fx4*>(Qout + base * 3 + 3072) + w * 192;
        const fx4* lsb = reinterpret_cast<const fx4*>(&lds[3072 + w * 768]);
        __builtin_nontemporal_store(lsb[l],       Qg1 + l);
        __builtin_nontemporal_store(lsb[l + 64],  Qg1 + l + 64);
        __builtin_nontemporal_store(lsb[l + 128], Qg1 + l + 128);
    } else {
        // ---- tail path: per-element guarded (not hit at la=25165824) ----
        for (int k = 0; k < 8; ++k) {
            const long e = base + t * 8 + k;
            if (e >= (long)la) break;
            const float xe = x[e];
            const float Q2 = fast_tanh(AMP * (xe - s2 + DLT));
            const float Q1 = fast_tanh(AMP * (xe - (b1 + (Q2 + 1.0f) * a1) + DLT));
            const float Q0 = fast_tanh(AMP * (xe - (b0 + (Q1 + 1.0f) * a01
                                                       + (Q2 + 1.0f) * a02) + DLT));
            out[e] = (Q0 + 1.0f) * w0 + (Q1 + 1.0f) * w1 + (Q2 + 1.0f) * w2;
            Qout[e * 3 + 0] = Q0;
            Qout[e * 3 + 1] = Q1;
            Qout[e * 3 + 2] = Q2;
        }
    }

    // Wn passthrough output: 6 floats at tail of out.
    if (blockIdx.x == 0 && t < 6) {
        out[(long)la * 4 + t] = W[t] + nz[t];
    }
}

extern "C" void kernel_launch(void* const* d_in, const int* in_sizes, int n_in,
                              void* d_out, int out_size, void* d_ws, size_t ws_size,
                              hipStream_t stream) {
    const float* x  = (const float*)d_in[0];
    const float* W  = (const float*)d_in[1];
    const float* nz = (const float*)d_in[2];
    float* out = (float*)d_out;
    const int la = in_sizes[0];            // 25165824

    const int block = 256;
    const int grid = (la + 2047) / 2048;   // 12288 blocks: 2048 elems each
    quant_kernel<<<grid, block, 0, stream>>>(x, W, nz, out, la);
}